// Round 1
// baseline (363.570 us; speedup 1.0000x reference)
//
#include <hip/hip_runtime.h>

#define MOD 242

static constexpr long long OFF_STATE = 1;
static constexpr long long OFF_SA    = 18433;
static constexpr long long OFF_SG    = 4478977;
static constexpr long long OFF_OG    = 4495361;
static constexpr long long OFF_GRAD  = 8955905;
static constexpr long long OFF_OWG   = 42510337;

#define WS_HID 0
#define WS_CON 16384
#define WS_COL 32768
#define WS_ROW 49152

// Fused pass over weights (134 MB, read once):
//   hidden[w,d]  = sum_i weights[i,w,d] * state[i,d]      (regs, then atomics)
//   contrib[i,d] = sum_w weights[i,w,d] * sgrad[w,d]      (butterfly + LDS, then atomics)
// Grid: 32 i-blocks (64 rows) x 16 w-blocks (128 cols) = 512 blocks.
__global__ __launch_bounds__(256) void k_matvec(
    const float* __restrict__ weights, const float* __restrict__ state,
    const float* __restrict__ sgrad, float* __restrict__ ws)
{
  const int b  = blockIdx.x;
  const int i0 = (b & 31) * 64;
  const int w0 = (b >> 5) * 128;
  const int tid = threadIdx.x;
  const int wv  = tid >> 6;
  const int l   = tid & 63;
  const int d4  = l & 1;            // which float4-half of d (0..3 / 4..7)
  const int w   = w0 + wv * 32 + (l >> 1);

  __shared__ __align__(16) float state_lds[64 * 8];
  __shared__ __align__(16) float contrib_lds[4][64][8];

  for (int idx = tid; idx < 64 * 8; idx += 256)
    state_lds[idx] = state[(size_t)(i0 + (idx >> 3)) * 9 + (idx & 7)];
  for (int idx = tid; idx < 4 * 64 * 8; idx += 256)
    (&contrib_lds[0][0][0])[idx] = 0.0f;
  __syncthreads();

  const float4 sg4 = *(const float4*)&sgrad[(size_t)w * 8 + d4 * 4];
  float4 h4 = make_float4(0.f, 0.f, 0.f, 0.f);
  const float* wp = weights + ((size_t)i0 * 2048 + w) * 8 + d4 * 4;

  #pragma unroll 4
  for (int ii = 0; ii < 64; ++ii) {
    const float4 w4 = *(const float4*)wp;
    wp += 16384;                            // next i row
    const float4 s4 = *(const float4*)&state_lds[ii * 8 + d4 * 4];
    h4.x = fmaf(w4.x, s4.x, h4.x);
    h4.y = fmaf(w4.y, s4.y, h4.y);
    h4.z = fmaf(w4.z, s4.z, h4.z);
    h4.w = fmaf(w4.w, s4.w, h4.w);

    float vx = w4.x * sg4.x, vy = w4.y * sg4.y, vz = w4.z * sg4.z, vw = w4.w * sg4.w;
    // butterfly over lanes sharing parity (same d4): masks 2,4,8,16,32
    #pragma unroll
    for (int m = 2; m <= 32; m <<= 1) {
      vx += __shfl_xor(vx, m);
      vy += __shfl_xor(vy, m);
      vz += __shfl_xor(vz, m);
      vw += __shfl_xor(vw, m);
    }
    if (l < 2) {                            // lane0 holds d=0..3, lane1 d=4..7
      float4* p = (float4*)&contrib_lds[wv][ii][l * 4];
      float4 o = *p;
      o.x += vx; o.y += vy; o.z += vz; o.w += vw;
      *p = o;
    }
  }

  atomicAdd(&ws[WS_HID + w * 8 + d4 * 4 + 0], h4.x);
  atomicAdd(&ws[WS_HID + w * 8 + d4 * 4 + 1], h4.y);
  atomicAdd(&ws[WS_HID + w * 8 + d4 * 4 + 2], h4.z);
  atomicAdd(&ws[WS_HID + w * 8 + d4 * 4 + 3], h4.w);

  __syncthreads();
  for (int idx = tid; idx < 64 * 8; idx += 256) {
    const int ii = idx >> 3, d = idx & 7;
    const float s = contrib_lds[0][ii][d] + contrib_lds[1][ii][d]
                  + contrib_lds[2][ii][d] + contrib_lds[3][ii][d];
    atomicAdd(&ws[WS_CON + (i0 + ii) * 8 + d], s);
  }
}

// Bulk copies of stored_activations -> sa and output_gradient -> og
// (time column fixed up later by k_finalize).
__global__ __launch_bounds__(256) void k_copy2(
    const float* __restrict__ a, float* __restrict__ da,
    const float* __restrict__ b, float* __restrict__ db, int n)
{
  const int stride = gridDim.x * blockDim.x;
  for (int i = blockIdx.x * blockDim.x + threadIdx.x; i < n; i += stride) {
    da[i] = a[i];
    db[i] = b[i];
  }
}

// Per-row (r in [0,2048)) epilogue: state, owg, output scalar, sg, sa/og time
// column, and colfac/rowfac staging for the gradients outer product.
__global__ __launch_bounds__(256) void k_finalize(
    const float* __restrict__ x, const float* __restrict__ ow,
    const float* __restrict__ sa_in, const float* __restrict__ og_in,
    const int* __restrict__ timep, float* __restrict__ ws, float* __restrict__ out)
{
  const int r = blockIdx.x * 256 + threadIdx.x;
  const int t = *timep;

  float s[9];
  s[0] = x[r];
  const float4 hA = *(const float4*)&ws[WS_HID + r * 8];
  const float4 hB = *(const float4*)&ws[WS_HID + r * 8 + 4];
  s[1] = fmaxf(hA.x, 0.f); s[2] = fmaxf(hA.y, 0.f);
  s[3] = fmaxf(hA.z, 0.f); s[4] = fmaxf(hA.w, 0.f);
  s[5] = fmaxf(hB.x, 0.f); s[6] = fmaxf(hB.y, 0.f);
  s[7] = fmaxf(hB.z, 0.f); s[8] = fmaxf(hB.w, 0.f);

  float owr[9];
  #pragma unroll
  for (int c = 0; c < 9; ++c) owr[c] = ow[(size_t)r * 9 + c];

  float p = 0.f;
  #pragma unroll
  for (int c = 0; c < 9; ++c) {
    out[OFF_STATE + (size_t)r * 9 + c] = s[c];
    out[OFF_OWG   + (size_t)r * 9 + c] = s[c];
    out[OFF_SA + ((size_t)r * 9 + c) * MOD + t] = s[c];
    out[OFF_OG + ((size_t)r * 9 + c) * MOD + t] = owr[c];
    p = fmaf(owr[c], s[c], p);
  }
  #pragma unroll
  for (int m = 1; m < 64; m <<= 1) p += __shfl_xor(p, m);
  if ((threadIdx.x & 63) == 0) atomicAdd(out, p);

  float con[8];
  const float4 cA = *(const float4*)&ws[WS_CON + r * 8];
  const float4 cB = *(const float4*)&ws[WS_CON + r * 8 + 4];
  con[0] = cA.x; con[1] = cA.y; con[2] = cA.z; con[3] = cA.w;
  con[4] = cB.x; con[5] = cB.y; con[6] = cB.z; con[7] = cB.w;

  float sg[8];
  #pragma unroll
  for (int a = 0; a < 7; ++a) {
    const int ti = (t + 2 * a - 14 + MOD) % MOD;
    const int tm = (ti + 1) % MOD;
    const float av  = (tm == t) ? s[a + 2] : sa_in[((size_t)r * 9 + a + 2) * MOD + tm];
    const float ogv = (ti == t) ? owr[a + 1] : og_in[((size_t)r * 9 + a + 1) * MOD + ti];
    sg[a] = (av > 0.f ? con[a + 1] : 0.f) + ogv;
  }
  sg[7] = owr[8];
  #pragma unroll
  for (int a = 0; a < 8; ++a) out[OFF_SG + (size_t)r * 8 + a] = sg[a];

  #pragma unroll
  for (int aa = 0; aa < 8; ++aa) {
    const int ti = (t + 2 * aa - 14 + MOD) % MOD;
    const int tp = (ti - 1 + MOD) % MOD;
    const float rv = (ti == t) ? s[aa + 1] : sa_in[((size_t)r * 9 + aa + 1) * MOD + ti];
    const float ap = (tp == t) ? s[aa]     : sa_in[((size_t)r * 9 + aa) * MOD + tp];
    ws[WS_COL + r * 8 + aa] = (rv > 0.f) ? sg[aa] : 0.f;  // sg * relu_g
    ws[WS_ROW + r * 8 + aa] = ap;                          // act_prev
  }
}

// gradients[i, j, a] = rowfac[i,a] * colfac[j,a]; one block per i, 134 MB write.
__global__ __launch_bounds__(256) void k_grad(
    const float* __restrict__ ws, float* __restrict__ out)
{
  const int i = blockIdx.x;
  const int tid = threadIdx.x;
  const float rf = ws[WS_ROW + i * 8 + (tid & 7)];   // a = tid&7, invariant over k
  float* o = out + OFF_GRAD + (size_t)i * 16384;
  const float* cf = ws + WS_COL;
  #pragma unroll 4
  for (int k = 0; k < 64; ++k) {
    const int e = k * 256 + tid;    // e = j*8 + a, consecutive -> coalesced
    o[e] = rf * cf[e];
  }
}

extern "C" void kernel_launch(void* const* d_in, const int* in_sizes, int n_in,
                              void* d_out, int out_size, void* d_ws, size_t ws_size,
                              hipStream_t stream)
{
  (void)in_sizes; (void)n_in; (void)out_size; (void)ws_size;
  const float* x     = (const float*)d_in[0];
  const float* wts   = (const float*)d_in[1];
  const float* ow    = (const float*)d_in[2];
  const float* st    = (const float*)d_in[3];
  const float* sa_in = (const float*)d_in[4];
  const float* sgrad = (const float*)d_in[5];
  const float* og_in = (const float*)d_in[6];
  const int*   timep = (const int*)d_in[7];
  float* out = (float*)d_out;
  float* ws  = (float*)d_ws;

  hipMemsetAsync(ws, 0, 32768 * sizeof(float), stream);   // hidden+contrib accumulators
  hipMemsetAsync(out, 0, sizeof(float), stream);          // output scalar

  k_matvec<<<512, 256, 0, stream>>>(wts, st, sgrad, ws);
  k_copy2<<<2048, 256, 0, stream>>>(sa_in, out + OFF_SA, og_in, out + OFF_OG, 4460544);
  k_finalize<<<8, 256, 0, stream>>>(x, ow, sa_in, og_in, timep, ws, out);
  k_grad<<<2048, 256, 0, stream>>>(ws, out);
}

// Round 2
// 343.877 us; speedup vs baseline: 1.0573x; 1.0573x over previous
//
#include <hip/hip_runtime.h>

#define MOD 242

static constexpr long long OFF_STATE = 1;
static constexpr long long OFF_SA    = 18433;
static constexpr long long OFF_SG    = 4478977;
static constexpr long long OFF_OG    = 4495361;
static constexpr long long OFF_GRAD  = 8955905;
static constexpr long long OFF_OWG   = 42510337;

// ws layout (floats). Partials are deterministic (no atomics, no memset needed).
#define WS_HID  0            // [32 iblk][2048 w][8 d]  hidden partials (2 MB)
#define WS_CON  524288       // [16 wblk][2048 i][8 d]  contrib partials (1 MB)
#define WS_COL  786432       // [2048][8] sg*relu_g
#define WS_ROW  802816       // [2048][8] act_prev
#define WS_OUTP 819200       // [32] per-block output partials

// ---- DPP wave-64 sum (VALU pipe only, no LDS). Result valid in lane 63. ----
template <int CTRL, int RM>
__device__ __forceinline__ float dppadd(float x) {
  int t = __builtin_amdgcn_update_dpp(0, __float_as_int(x), CTRL, RM, 0xF, true);
  return x + __int_as_float(t);
}
__device__ __forceinline__ float wave_sum_dpp(float x) {
  x = dppadd<0x111, 0xF>(x);   // row_shr:1
  x = dppadd<0x112, 0xF>(x);   // row_shr:2
  x = dppadd<0x114, 0xF>(x);   // row_shr:4
  x = dppadd<0x118, 0xF>(x);   // row_shr:8  -> lane15 of each row = row sum
  x = dppadd<0x142, 0xA>(x);   // row_bcast:15 into rows 1,3
  x = dppadd<0x143, 0xC>(x);   // row_bcast:31 into rows 2,3 -> lane63 = total
  return x;
}

// Fused single pass over weights (134 MB read once):
//   hidden[w,d]  = sum_i weights[i,w,d] * state[i,d]   (registers -> partial store)
//   contrib[i,d] = sum_w weights[i,w,d] * sgrad[w,d]   (DPP wave reduction)
// Lane layout: lane l = w offset (64 consecutive w per wave); wave = (wgrp, dhalf).
__global__ __launch_bounds__(256) void k_matvec(
    const float* __restrict__ weights, const float* __restrict__ state,
    const float* __restrict__ sgrad, float* __restrict__ ws)
{
  const int b    = blockIdx.x;
  const int iblk = b & 31;
  const int wblk = b >> 5;
  const int i0   = iblk * 64;
  const int w0   = wblk * 128;
  const int tid  = threadIdx.x;
  const int wv   = tid >> 6;
  const int l    = tid & 63;
  const int wgrp = wv >> 1;          // which 64-w group
  const int dh   = wv & 1;           // which float4 half of d
  const int w    = w0 + wgrp * 64 + l;

  __shared__ __align__(16) float state_lds[64 * 8];
  __shared__ __align__(16) float cl[4][64][4];   // per-wave contrib partials

  for (int idx = tid; idx < 64 * 8; idx += 256)
    state_lds[idx] = state[(size_t)(i0 + (idx >> 3)) * 9 + (idx & 7)];
  __syncthreads();

  const float4 sg4 = *(const float4*)&sgrad[(size_t)w * 8 + dh * 4];
  float4 h4 = make_float4(0.f, 0.f, 0.f, 0.f);
  const float* wp = weights + ((size_t)i0 * 2048 + w) * 8 + dh * 4;

  #pragma unroll 4
  for (int ii = 0; ii < 64; ++ii) {
    const float4 w4 = *(const float4*)wp;
    wp += 16384;                                        // next i row
    const float4 s4 = *(const float4*)&state_lds[ii * 8 + dh * 4]; // broadcast

    h4.x = fmaf(w4.x, s4.x, h4.x);
    h4.y = fmaf(w4.y, s4.y, h4.y);
    h4.z = fmaf(w4.z, s4.z, h4.z);
    h4.w = fmaf(w4.w, s4.w, h4.w);

    float vx = wave_sum_dpp(w4.x * sg4.x);
    float vy = wave_sum_dpp(w4.y * sg4.y);
    float vz = wave_sum_dpp(w4.z * sg4.z);
    float vw = wave_sum_dpp(w4.w * sg4.w);
    if (l == 63)
      *(float4*)&cl[wv][ii][0] = make_float4(vx, vy, vz, vw);
  }

  // hidden partial: [iblk][w][d], each lane owns (w, dhalf)
  *(float4*)&ws[WS_HID + ((size_t)iblk * 2048 + w) * 8 + dh * 4] = h4;

  __syncthreads();
  // contrib partial: combine the two w-groups; [wblk][i][d]
  {
    const int ii = tid >> 2, q = tid & 3;
    const float c0 = cl[0][ii][q] + cl[2][ii][q];   // d = q
    const float c1 = cl[1][ii][q] + cl[3][ii][q];   // d = q + 4
    const size_t base = WS_CON + ((size_t)wblk * 2048 + i0 + ii) * 8;
    ws[base + q]     = c0;
    ws[base + 4 + q] = c1;
  }
}

// Bulk copies (time column fixed by k_finalize). Scalar but fully coalesced;
// dst offsets are odd so float4 stores would be misaligned. 4460544 = 256*17424.
__global__ __launch_bounds__(256) void k_copy2(
    const float* __restrict__ a, float* __restrict__ da,
    const float* __restrict__ b, float* __restrict__ db)
{
  const int i = blockIdx.x * 256 + threadIdx.x;
  da[i] = a[i];
  db[i] = b[i];
}

// Per-row epilogue: reduce partials, state/owg/output/sg, sa/og time column,
// colfac/rowfac staging. Grid 32 x 64 (one wave per block).
__global__ __launch_bounds__(64) void k_finalize(
    const float* __restrict__ x, const float* __restrict__ ow,
    const float* __restrict__ sa_in, const float* __restrict__ og_in,
    const int* __restrict__ timep, float* __restrict__ ws, float* __restrict__ out)
{
  const int r = blockIdx.x * 64 + threadIdx.x;
  const int t = *timep;

  float hid[8] = {0,0,0,0,0,0,0,0};
  {
    const float4* hp = (const float4*)&ws[WS_HID + (size_t)r * 8];
    #pragma unroll
    for (int ib = 0; ib < 32; ++ib) {
      const float4 pa = hp[(size_t)ib * 4096];
      const float4 pb = hp[(size_t)ib * 4096 + 1];
      hid[0] += pa.x; hid[1] += pa.y; hid[2] += pa.z; hid[3] += pa.w;
      hid[4] += pb.x; hid[5] += pb.y; hid[6] += pb.z; hid[7] += pb.w;
    }
  }
  float con[8] = {0,0,0,0,0,0,0,0};
  {
    const float4* cp = (const float4*)&ws[WS_CON + (size_t)r * 8];
    #pragma unroll
    for (int wb = 0; wb < 16; ++wb) {
      const float4 pa = cp[(size_t)wb * 4096];
      const float4 pb = cp[(size_t)wb * 4096 + 1];
      con[0] += pa.x; con[1] += pa.y; con[2] += pa.z; con[3] += pa.w;
      con[4] += pb.x; con[5] += pb.y; con[6] += pb.z; con[7] += pb.w;
    }
  }

  float s[9];
  s[0] = x[r];
  #pragma unroll
  for (int d = 0; d < 8; ++d) s[d + 1] = fmaxf(hid[d], 0.f);

  float owr[9];
  #pragma unroll
  for (int c = 0; c < 9; ++c) owr[c] = ow[(size_t)r * 9 + c];

  float p = 0.f;
  #pragma unroll
  for (int c = 0; c < 9; ++c) {
    out[OFF_STATE + (size_t)r * 9 + c] = s[c];
    out[OFF_OWG   + (size_t)r * 9 + c] = s[c];
    out[OFF_SA + ((size_t)r * 9 + c) * MOD + t] = s[c];
    out[OFF_OG + ((size_t)r * 9 + c) * MOD + t] = owr[c];
    p = fmaf(owr[c], s[c], p);
  }
  #pragma unroll
  for (int m = 1; m < 64; m <<= 1) p += __shfl_xor(p, m);
  if (threadIdx.x == 0) ws[WS_OUTP + blockIdx.x] = p;

  float sg[8];
  #pragma unroll
  for (int a = 0; a < 7; ++a) {
    const int ti = (t + 2 * a - 14 + MOD) % MOD;
    const int tm = (ti + 1) % MOD;
    const float av  = (tm == t) ? s[a + 2] : sa_in[((size_t)r * 9 + a + 2) * MOD + tm];
    const float ogv = (ti == t) ? owr[a + 1] : og_in[((size_t)r * 9 + a + 1) * MOD + ti];
    sg[a] = (av > 0.f ? con[a + 1] : 0.f) + ogv;
  }
  sg[7] = owr[8];
  #pragma unroll
  for (int a = 0; a < 8; ++a) out[OFF_SG + (size_t)r * 8 + a] = sg[a];

  #pragma unroll
  for (int aa = 0; aa < 8; ++aa) {
    const int ti = (t + 2 * aa - 14 + MOD) % MOD;
    const int tp = (ti - 1 + MOD) % MOD;
    const float rv = (ti == t) ? s[aa + 1] : sa_in[((size_t)r * 9 + aa + 1) * MOD + ti];
    const float ap = (tp == t) ? s[aa]     : sa_in[((size_t)r * 9 + aa) * MOD + tp];
    ws[WS_COL + r * 8 + aa] = (rv > 0.f) ? sg[aa] : 0.f;
    ws[WS_ROW + r * 8 + aa] = ap;
  }
}

// gradients[i,j,a] = rowfac[i,a] * colfac[j,a]; 134 MB coalesced write.
// Also finishes the output scalar (partials written by k_finalize).
__global__ __launch_bounds__(256) void k_grad(
    const float* __restrict__ ws, float* __restrict__ out)
{
  const int i = blockIdx.x;
  const int tid = threadIdx.x;
  if (i == 0 && tid == 0) {
    float s = 0.f;
    #pragma unroll
    for (int k = 0; k < 32; ++k) s += ws[WS_OUTP + k];
    out[0] = s;
  }
  const float rf = ws[WS_ROW + i * 8 + (tid & 7)];
  float* o = out + OFF_GRAD + (size_t)i * 16384;
  const float* cf = ws + WS_COL;
  #pragma unroll 4
  for (int k = 0; k < 64; ++k) {
    const int e = k * 256 + tid;
    o[e] = rf * cf[e];
  }
}

extern "C" void kernel_launch(void* const* d_in, const int* in_sizes, int n_in,
                              void* d_out, int out_size, void* d_ws, size_t ws_size,
                              hipStream_t stream)
{
  (void)in_sizes; (void)n_in; (void)out_size; (void)ws_size;
  const float* x     = (const float*)d_in[0];
  const float* wts   = (const float*)d_in[1];
  const float* ow    = (const float*)d_in[2];
  const float* st    = (const float*)d_in[3];
  const float* sa_in = (const float*)d_in[4];
  const float* sgrad = (const float*)d_in[5];
  const float* og_in = (const float*)d_in[6];
  const int*   timep = (const int*)d_in[7];
  float* out = (float*)d_out;
  float* ws  = (float*)d_ws;

  k_matvec<<<512, 256, 0, stream>>>(wts, st, sgrad, ws);
  k_copy2<<<17424, 256, 0, stream>>>(sa_in, out + OFF_SA, og_in, out + OFF_OG);
  k_finalize<<<32, 64, 0, stream>>>(x, ow, sa_in, og_in, timep, ws, out);
  k_grad<<<2048, 256, 0, stream>>>(ws, out);
}